// Round 19
// baseline (2512.566 us; speedup 1.0000x reference)
//
#include <hip/hip_runtime.h>
#include <hip/hip_fp16.h>
#include <math.h>
#include <stdint.h>

#define DIM 10
#define NTILE 256
#define BKT_LOG 8
#define BKT 256                   // nodes per bucket == threads per WG
#define NBMAX 2048
#define EPW 2048                  // edges per WG in binning
#define KPT (EPW / 256)
#define NPART 8                   // send partitions (s>>16: 64K nodes = 2MB h16)
#define PSHIFT 16
#define CAP 448                   // slots per (p,b) cell: mean 288 + 9.4 sigma
#define OVFCAP 32768
#define D2WORDS 32768
#define XSTR 11                   // xl LDS stride (coprime with 32 banks)
#define BARSLOTS 8                // arrival sub-counters per phase (contention split)
#define BARWORDS (2 * NPART * BARSLOTS)   // both iterations
#define TIMEOUT_TICKS 4000        // ~40 us at 100 MHz realtime clock (perf-only cap)

// meta (u32): cnt[NPART*NBMAX] | ovfc[8] | bar[BARWORDS] | ovf[OVFCAP] | depth2[D2WORDS]
// ws: h16a[n*16 u16] | h16b[n*16 u16] | bins[NPART*NB*CAP u32] | meta

struct GruW {
    const float *Wz, *bz, *Uz, *buz, *Wr, *br, *Ur, *bur, *Wh, *bh, *Uh, *buh;
};

__device__ __forceinline__ float2 cvt2(uint32_t u) {
    __half2 hh = *reinterpret_cast<__half2*>(&u);
    return __half22float2(hh);
}

__device__ __forceinline__ int d2get(const uint32_t* __restrict__ depth2, int node) {
    uint32_t w = depth2[(uint32_t)node >> 4];
    return (int)((w >> ((node & 15) * 2)) & 3u);
}

// ---------------------------------------------------------------------------
// prep: [0,pack) pack depth->2b | rest zero cnt + ovfc + bar
// ---------------------------------------------------------------------------
__global__ void prep_kernel(const int* __restrict__ depth,
                            uint32_t* __restrict__ depth2,
                            uint32_t* __restrict__ cnts,
                            int n, int pack_blocks, int cnt_tot)
{
    __shared__ int sd[4096];
    const int t = threadIdx.x;
    const int bid = blockIdx.x;
    if (bid < pack_blocks) {
        const int base = bid * 4096;
        for (int i = t; i < 4096; i += 256) {
            int g = base + i;
            sd[i] = (g < n) ? depth[g] : 3;
        }
        __syncthreads();
        int wb = (base >> 4) + t;
        if (wb * 16 < n) {
            uint32_t v = 0;
            #pragma unroll
            for (int j = 0; j < 16; ++j)
                v |= ((uint32_t)(sd[t * 16 + j] & 3)) << (2 * j);
            depth2[wb] = v;
        }
    } else {
        int i = (bid - pack_blocks) * 256 + t;
        if (i < cnt_tot) cnts[i] = 0;
    }
}

// ---------------------------------------------------------------------------
// binit: blocks [0,bin_blocks) bin edges into (p,b) cells; rest init h16a.
// word = s(19b) | rl(8b)<<19 | flag(useful@iter1)<<27
// ---------------------------------------------------------------------------
__global__ __launch_bounds__(256) void binit_kernel(
                           const int* __restrict__ recv,
                           const int* __restrict__ send,
                           const uint32_t* __restrict__ depth2,
                           const int* __restrict__ depth,
                           const float* __restrict__ h_in,
                           uint16_t* __restrict__ h16a,
                           uint32_t* __restrict__ cnt,
                           uint32_t* __restrict__ ovfc,
                           uint32_t* __restrict__ ovf,
                           uint32_t* __restrict__ bins,
                           int ne, int n, int NB, int bin_blocks)
{
    __shared__ float sh[NTILE * 11];
    const int t = threadIdx.x;
    const int bid = blockIdx.x;

    if (bid < bin_blocks) {
        const int base = bid * EPW;
        int rA[KPT], sA[KPT];
        #pragma unroll
        for (int k = 0; k < KPT; ++k) {
            int e = base + k * 256 + t;
            if (e < ne) { rA[k] = recv[e]; sA[k] = send[e]; }
            else        { rA[k] = -1;      sA[k] = 0;       }
        }
        int drA[KPT], dsA[KPT];
        #pragma unroll
        for (int k = 0; k < KPT; ++k) {
            if (rA[k] >= 0) { drA[k] = d2get(depth2, rA[k]); dsA[k] = d2get(depth2, sA[k]); }
            else            { drA[k] = 3;                    dsA[k] = 3;                    }
        }
        #pragma unroll
        for (int k = 0; k < KPT; ++k) {
            if (rA[k] >= 0 && drA[k] <= 2 && dsA[k] <= 2) {
                int r = rA[k], s = sA[k];
                bool f1 = (drA[k] <= 1) && (dsA[k] <= 1);
                uint32_t w = (uint32_t)s | ((uint32_t)(r & (BKT - 1)) << 19)
                           | (f1 ? (1u << 27) : 0u);
                int cell = (s >> PSHIFT) * NB + (r >> BKT_LOG);
                uint32_t pos = atomicAdd(&cnt[cell], 1u);
                if (pos < CAP) bins[(size_t)cell * CAP + pos] = w;
                else { uint32_t oi = atomicAdd(ovfc, 1u);
                       if (oi < OVFCAP) ovf[oi] = (uint32_t)(base + k * 256 + t); }
            }
        }
    } else {
        // init: h16a[node] = fp16( (depth<=2) ? h_in[node] : 0 ), pads 0
        const int base = (bid - bin_blocks) * NTILE;
        const long gbase = (long)base * DIM;
        const long glim  = (long)n * DIM;
        for (int idx = t; idx < NTILE * DIM; idx += NTILE) {
            long g = gbase + idx;
            float v = (g < glim) ? h_in[g] : 0.0f;
            sh[(idx / DIM) * 11 + (idx % DIM)] = v;
        }
        __syncthreads();
        const int node = base + t;
        if (node < n && depth[node] > 2) {
            #pragma unroll
            for (int c = 0; c < DIM; ++c) sh[t * 11 + c] = 0.0f;
        }
        __syncthreads();
        uint32_t* o16 = reinterpret_cast<uint32_t*>(h16a);
        const long o16base = (long)base * 8;
        const long o16lim  = (long)n * 8;
        for (int idx = t; idx < NTILE * 8; idx += NTILE) {
            long g = o16base + idx;
            if (g < o16lim) {
                int nl = idx / 8, c2 = idx % 8;
                uint32_t w = 0;
                if (c2 < 5) {
                    __half2 hh = __floats2half2_rn(sh[nl * 11 + 2 * c2],
                                                   sh[nl * 11 + 2 * c2 + 1]);
                    w = *reinterpret_cast<uint32_t*>(&hh);
                }
                o16[g] = w;
            }
        }
    }
}

// ---------------------------------------------------------------------------
// fused scatter + GRU with partition phasing.
// Barrier mechanics (perf-only, wall-clock-bounded, can never deadlock):
//  - arrival: device-scope atomicAdd(+1) on one of 8 sub-counters (b&7)
//    -> arrival RMWs spread over 8 lines, ~8x less serialization
//  - poll: system-scope plain loads (sc0+sc1 -> bypass non-coherent per-XCD
//    L2, read the LLC coherence point). Loads don't enter the RMW queue.
//  - timeout: s_memrealtime wall clock, ~40us cap per barrier.
// ---------------------------------------------------------------------------
template<int ITER, int COOP>
__global__ __launch_bounds__(256, 8) void scatgru_kernel(
                            const uint32_t* __restrict__ bins,
                            const uint32_t* __restrict__ cnt,
                            const uint32_t* __restrict__ ovfc,
                            const uint32_t* __restrict__ ovf,
                            const int* __restrict__ recv,
                            const int* __restrict__ send,
                            const int* __restrict__ depth,
                            const uint16_t* __restrict__ hcur,  // stride 16 halfs
                            uint16_t* __restrict__ hnext,       // ITER==0 out
                            float* __restrict__ out32,          // ITER==1 out
                            uint32_t* bar,                      // NPART*BARSLOTS
                            int n, int NB, GruW w)
{
    __shared__ float xl[BKT * XSTR];     // 11264 B
    __shared__ float sW[6][100];
    __shared__ float sb[3][10];

    const int t = threadIdx.x;
    if (t < 100) {
        sW[0][t] = w.Wz[t]; sW[1][t] = w.Uz[t];
        sW[2][t] = w.Wr[t]; sW[3][t] = w.Ur[t];
        sW[4][t] = w.Wh[t]; sW[5][t] = w.Uh[t];
    }
    if (t < 10) {
        sb[0][t] = w.bz[t] + w.buz[t];
        sb[1][t] = w.br[t] + w.bur[t];
        sb[2][t] = w.bh[t] + w.buh[t];
    }
    for (int i = t; i < BKT * XSTR; i += 256) xl[i] = 0.0f;
    __syncthreads();

    const int b = blockIdx.x;
    const int n0 = b << BKT_LOG;
    const int nb = min(BKT, n - n0);

    // phase 1: partition-phased gather + LDS accumulate
    for (int p = 0; p < NPART; ++p) {
        const int cell = p * NB + b;
        const size_t base = (size_t)cell * CAP;
        const int tot = (int)min(cnt[cell], (uint32_t)CAP);
        for (int i = t; i < tot; i += 256) {
            uint32_t ww = bins[base + i];
            if (ITER == 1 && !((ww >> 27) & 1u)) continue;
            size_t s = (size_t)(ww & 0x7FFFFu);
            uint4 q = *reinterpret_cast<const uint4*>(hcur + s * 16);
            uint32_t e8 = *reinterpret_cast<const uint32_t*>(hcur + s * 16 + 8);
            float2 f0 = cvt2(q.x), f1 = cvt2(q.y), f2 = cvt2(q.z), f3 = cvt2(q.w);
            float2 f4 = cvt2(e8);
            float* xr = xl + ((ww >> 19) & (BKT - 1)) * XSTR;
            atomicAdd(xr + 0, f0.x); atomicAdd(xr + 1, f0.y);
            atomicAdd(xr + 2, f1.x); atomicAdd(xr + 3, f1.y);
            atomicAdd(xr + 4, f2.x); atomicAdd(xr + 5, f2.y);
            atomicAdd(xr + 6, f3.x); atomicAdd(xr + 7, f3.y);
            atomicAdd(xr + 8, f4.x); atomicAdd(xr + 9, f4.y);
        }
        if (COOP && p + 1 < NPART) {
            __syncthreads();
            if (t == 0) {
                uint32_t* bp = bar + p * BARSLOTS;
                atomicAdd(&bp[b & (BARSLOTS - 1)], 1u);
                const uint64_t t0 = __builtin_amdgcn_s_memrealtime();
                for (;;) {
                    uint32_t sum = 0;
                    #pragma unroll
                    for (int k = 0; k < BARSLOTS; ++k)
                        sum += __hip_atomic_load(&bp[k], __ATOMIC_RELAXED,
                                                 __HIP_MEMORY_SCOPE_SYSTEM);
                    if (sum >= (uint32_t)gridDim.x) break;
                    if (__builtin_amdgcn_s_memrealtime() - t0 > TIMEOUT_TICKS) break;
                    __builtin_amdgcn_s_sleep(8);
                }
            }
            __syncthreads();
        }
    }

    // phase 2: rare overflow edges for this bucket
    {
        const uint32_t cntv = min(*ovfc, (uint32_t)OVFCAP);
        for (uint32_t i = t; i < cntv; i += 256) {
            int e = (int)ovf[i];
            int r = recv[e];
            if ((r >> BKT_LOG) != b) continue;
            int s = send[e];
            if (ITER == 1 && (depth[r] > 1 || depth[s] > 1)) continue;
            uint4 q = *reinterpret_cast<const uint4*>(hcur + (size_t)s * 16);
            uint32_t e8v = *reinterpret_cast<const uint32_t*>(hcur + (size_t)s * 16 + 8);
            float2 f0 = cvt2(q.x), f1 = cvt2(q.y), f2 = cvt2(q.z), f3 = cvt2(q.w);
            float2 f4 = cvt2(e8v);
            float* xr = xl + (r & (BKT - 1)) * XSTR;
            atomicAdd(xr + 0, f0.x); atomicAdd(xr + 1, f0.y);
            atomicAdd(xr + 2, f1.x); atomicAdd(xr + 3, f1.y);
            atomicAdd(xr + 4, f2.x); atomicAdd(xr + 5, f2.y);
            atomicAdd(xr + 6, f3.x); atomicAdd(xr + 7, f3.y);
            atomicAdd(xr + 8, f4.x); atomicAdd(xr + 9, f4.y);
        }
    }
    __syncthreads();

    // phase 3: GRU for node n0+t (register-dieted)
    if (t < nb) {
        const int node = n0 + t;
        const int dep = depth[node];
        const bool active = (dep + ITER) <= 2;

        float hv[DIM];
        {
            const uint16_t* hp = hcur + (size_t)node * 16;
            uint4 q = *reinterpret_cast<const uint4*>(hp);
            uint32_t e8v = *reinterpret_cast<const uint32_t*>(hp + 8);
            float2 f0 = cvt2(q.x), f1 = cvt2(q.y), f2 = cvt2(q.z), f3 = cvt2(q.w);
            float2 f4 = cvt2(e8v);
            hv[0] = f0.x; hv[1] = f0.y; hv[2] = f1.x; hv[3] = f1.y;
            hv[4] = f2.x; hv[5] = f2.y; hv[6] = f3.x; hv[7] = f3.y;
            hv[8] = f4.x; hv[9] = f4.y;
        }
        float xv[DIM];
        #pragma unroll
        for (int j = 0; j < DIM; ++j) xv[j] = xl[t * XSTR + j];

        float zz[DIM];
        if (active) {
            #pragma unroll
            for (int i = 0; i < DIM; ++i) {
                float az = sb[0][i];
                float ar = sb[1][i];
                #pragma unroll
                for (int j = 0; j < DIM; ++j) {
                    az = fmaf(xv[j], sW[0][i * DIM + j], az);
                    az = fmaf(hv[j], sW[1][i * DIM + j], az);
                    ar = fmaf(xv[j], sW[2][i * DIM + j], ar);
                    ar = fmaf(hv[j], sW[3][i * DIM + j], ar);
                }
                zz[i] = 1.0f / (1.0f + __expf(-az));
                xl[t * XSTR + i] = (1.0f / (1.0f + __expf(-ar))) * hv[i];  // rh
            }
        }

        if (ITER == 0) {
            uint32_t packed[5];
            float prev = 0.0f;
            #pragma unroll
            for (int i = 0; i < DIM; ++i) {
                float o;
                if (active) {
                    float ah = sb[2][i];
                    #pragma unroll
                    for (int j = 0; j < DIM; ++j) {
                        ah = fmaf(xv[j], sW[4][i * DIM + j], ah);
                        ah = fmaf(xl[t * XSTR + j], sW[5][i * DIM + j], ah);
                    }
                    o = zz[i] * hv[i] + (1.0f - zz[i]) * tanhf(ah);
                } else {
                    o = hv[i];
                }
                if (dep > 1) o = 0.0f;     // fold iter-1 mask
                if (i & 1) {
                    __half2 hh = __floats2half2_rn(prev, o);
                    packed[i >> 1] = *reinterpret_cast<uint32_t*>(&hh);
                } else prev = o;
            }
            uint4 o0 = make_uint4(packed[0], packed[1], packed[2], packed[3]);
            uint4 o1 = make_uint4(packed[4], 0u, 0u, 0u);
            *reinterpret_cast<uint4*>(hnext + (size_t)node * 16)     = o0;
            *reinterpret_cast<uint4*>(hnext + (size_t)node * 16 + 8) = o1;
        } else {
            float2* op = reinterpret_cast<float2*>(out32 + (size_t)node * DIM);
            float prev = 0.0f;
            #pragma unroll
            for (int i = 0; i < DIM; ++i) {
                float o;
                if (active) {
                    float ah = sb[2][i];
                    #pragma unroll
                    for (int j = 0; j < DIM; ++j) {
                        ah = fmaf(xv[j], sW[4][i * DIM + j], ah);
                        ah = fmaf(xl[t * XSTR + j], sW[5][i * DIM + j], ah);
                    }
                    o = zz[i] * hv[i] + (1.0f - zz[i]) * tanhf(ah);
                } else {
                    o = hv[i];
                }
                if (i & 1) op[i >> 1] = make_float2(prev, o);
                else prev = o;
            }
        }
    }
}

// ---------------------------------------------------------------------------
// fallback path (ws too small / n too large): fp32 global-atomic pipeline
// ---------------------------------------------------------------------------
__global__ void init_mask32_kernel(const float* __restrict__ hsrc,
                                   float* __restrict__ hdst,
                                   const int* __restrict__ depth, int n)
{
    int node = blockIdx.x * blockDim.x + threadIdx.x;
    if (node >= n) return;
    bool act = depth[node] <= 2;
    const float* s = hsrc + (size_t)node * DIM;
    float* d = hdst + (size_t)node * DIM;
    #pragma unroll
    for (int c = 0; c < DIM; ++c) d[c] = act ? s[c] : 0.0f;
}

__global__ void simple_scatter_kernel(const int* __restrict__ recv,
                                      const int* __restrict__ send,
                                      const float* __restrict__ hm,
                                      float* __restrict__ x, int ne)
{
    const int tid = blockIdx.x * blockDim.x + threadIdx.x;
    const int e = tid / DIM;
    if (e >= ne) return;
    const int c = tid - e * DIM;
    const int s = send[e];
    const float v = hm[(size_t)s * DIM + c];
    if (v != 0.0f) {
        const int r = recv[e];
        unsafeAtomicAdd(x + (size_t)r * DIM + c, v);
    }
}

__global__ void zero_buf_kernel(float4* __restrict__ p, int tot4) {
    int i = blockIdx.x * blockDim.x + threadIdx.x;
    if (i < tot4) p[i] = make_float4(0.0f, 0.0f, 0.0f, 0.0f);
}

__global__ void gru32_kernel(const float* __restrict__ x,
                             const float* __restrict__ h,
                             float* __restrict__ out,
                             const int* __restrict__ depth, int iter, int n, GruW w)
{
    __shared__ float sW[6][100];
    __shared__ float sb[3][10];
    const int t = threadIdx.x;
    if (t < 100) {
        sW[0][t] = w.Wz[t]; sW[1][t] = w.Uz[t];
        sW[2][t] = w.Wr[t]; sW[3][t] = w.Ur[t];
        sW[4][t] = w.Wh[t]; sW[5][t] = w.Uh[t];
    }
    if (t < 10) {
        sb[0][t] = w.bz[t] + w.buz[t];
        sb[1][t] = w.br[t] + w.bur[t];
        sb[2][t] = w.bh[t] + w.buh[t];
    }
    __syncthreads();

    int node = blockIdx.x * blockDim.x + t;
    if (node >= n) return;
    const int dep = depth[node];
    const bool active = dep + iter <= 2;
    float xv[DIM], hv[DIM], outv[DIM];
    #pragma unroll
    for (int j = 0; j < DIM; ++j) {
        xv[j] = x[(size_t)node * DIM + j];
        hv[j] = h[(size_t)node * DIM + j];
    }
    if (active) {
        float zz[DIM], rh[DIM];
        #pragma unroll
        for (int i = 0; i < DIM; ++i) {
            float az = sb[0][i], ar = sb[1][i];
            #pragma unroll
            for (int j = 0; j < DIM; ++j) {
                az = fmaf(xv[j], sW[0][i * DIM + j], az);
                az = fmaf(hv[j], sW[1][i * DIM + j], az);
                ar = fmaf(xv[j], sW[2][i * DIM + j], ar);
                ar = fmaf(hv[j], sW[3][i * DIM + j], ar);
            }
            zz[i] = 1.0f / (1.0f + __expf(-az));
            rh[i] = (1.0f / (1.0f + __expf(-ar))) * hv[i];
        }
        #pragma unroll
        for (int i = 0; i < DIM; ++i) {
            float ah = sb[2][i];
            #pragma unroll
            for (int j = 0; j < DIM; ++j) {
                ah = fmaf(xv[j], sW[4][i * DIM + j], ah);
                ah = fmaf(rh[j], sW[5][i * DIM + j], ah);
            }
            outv[i] = zz[i] * hv[i] + (1.0f - zz[i]) * tanhf(ah);
        }
    } else {
        #pragma unroll
        for (int i = 0; i < DIM; ++i) outv[i] = hv[i];
    }
    if (iter == 0 && dep > 1) {
        #pragma unroll
        for (int i = 0; i < DIM; ++i) outv[i] = 0.0f;
    }
    #pragma unroll
    for (int i = 0; i < DIM; ++i) out[(size_t)node * DIM + i] = outv[i];
}

extern "C" void kernel_launch(void* const* d_in, const int* in_sizes, int n_in,
                              void* d_out, int out_size, void* d_ws, size_t ws_size,
                              hipStream_t stream) {
    const float* h_in  = (const float*)d_in[0];
    const int*   edges = (const int*)d_in[1];
    const int*   depth = (const int*)d_in[2];
    GruW gw;
    gw.Wz  = (const float*)d_in[3];  gw.bz  = (const float*)d_in[4];
    gw.Uz  = (const float*)d_in[5];  gw.buz = (const float*)d_in[6];
    gw.Wr  = (const float*)d_in[7];  gw.br  = (const float*)d_in[8];
    gw.Ur  = (const float*)d_in[9];  gw.bur = (const float*)d_in[10];
    gw.Wh  = (const float*)d_in[11]; gw.bh  = (const float*)d_in[12];
    gw.Uh  = (const float*)d_in[13]; gw.buh = (const float*)d_in[14];

    const int n  = in_sizes[0] / DIM;       // 500,000
    const int ne = in_sizes[1] / 2;         // 8,000,000
    const int* recv = edges;
    const int* send = edges + ne;

    const int NB = (n + BKT - 1) >> BKT_LOG;
    const size_t meta_words = (size_t)NPART * NBMAX + 8 + BARWORDS + OVFCAP + D2WORDS;
    const size_t need = (size_t)n * 16 * sizeof(uint16_t) * 2            // h16a+h16b
                      + (size_t)NPART * NB * CAP * sizeof(uint32_t)      // bins
                      + meta_words * sizeof(uint32_t);

    const int BLK = 256;

    if (ws_size >= need && n <= (1 << 19) && NB <= NBMAX && out_size >= n * DIM) {
        uint16_t* h16a = (uint16_t*)d_ws;
        uint16_t* h16b = h16a + (size_t)n * 16;
        uint32_t* bins = (uint32_t*)(h16b + (size_t)n * 16);
        uint32_t* meta = bins + (size_t)NPART * NB * CAP;
        uint32_t* cnt    = meta;                             // NPART*NBMAX
        uint32_t* ovfc   = meta + (size_t)NPART * NBMAX;     // 8
        uint32_t* bar    = ovfc + 8;                         // BARWORDS
        uint32_t* ovf    = bar + BARWORDS;                   // OVFCAP
        uint32_t* depth2 = ovf + OVFCAP;                     // D2WORDS

        const int bin_blocks  = (ne + EPW - 1) / EPW;
        const int node_blocks = (n + NTILE - 1) / NTILE;
        const int pack_blocks = (n + 4095) / 4096;
        const int cnt_tot = NPART * NBMAX + 8 + BARWORDS;    // cnt + ovfc + bar
        const int cnt_blocks = (cnt_tot + 255) / 256;

        prep_kernel<<<pack_blocks + cnt_blocks, BLK, 0, stream>>>(
            depth, depth2, cnt, n, pack_blocks, cnt_tot);
        binit_kernel<<<bin_blocks + node_blocks, BLK, 0, stream>>>(
            recv, send, depth2, depth, h_in, h16a,
            cnt, ovfc, ovf, bins, ne, n, NB, bin_blocks);

        float* out32 = (float*)d_out;
        float* nullf = nullptr;
        uint16_t* nullh = nullptr;
        int n_ = n, NB_ = NB;
        uint32_t* bar0 = bar;
        uint32_t* bar1 = bar + NPART * BARSLOTS;

        // ---- iteration 0 (cooperative; split-counter + system-load barrier) ----
        {
            void* args[] = { (void*)&bins, (void*)&cnt, (void*)&ovfc, (void*)&ovf,
                             (void*)&recv, (void*)&send, (void*)&depth,
                             (void*)&h16a, (void*)&h16b, (void*)&nullf,
                             (void*)&bar0, (void*)&n_, (void*)&NB_, (void*)&gw };
            hipError_t err = hipLaunchCooperativeKernel(
                reinterpret_cast<const void*>(&scatgru_kernel<0, 1>),
                dim3(NB), dim3(BLK), args, 0, stream);
            if (err != hipSuccess) {
                scatgru_kernel<0, 0><<<NB, BLK, 0, stream>>>(
                    bins, cnt, ovfc, ovf, recv, send, depth,
                    h16a, h16b, nullptr, bar0, n, NB, gw);
            }
        }

        // ---- iteration 1 ----
        {
            void* args[] = { (void*)&bins, (void*)&cnt, (void*)&ovfc, (void*)&ovf,
                             (void*)&recv, (void*)&send, (void*)&depth,
                             (void*)&h16b, (void*)&nullh, (void*)&out32,
                             (void*)&bar1, (void*)&n_, (void*)&NB_, (void*)&gw };
            hipError_t err = hipLaunchCooperativeKernel(
                reinterpret_cast<const void*>(&scatgru_kernel<1, 1>),
                dim3(NB), dim3(BLK), args, 0, stream);
            if (err != hipSuccess) {
                scatgru_kernel<1, 0><<<NB, BLK, 0, stream>>>(
                    bins, cnt, ovfc, ovf, recv, send, depth,
                    h16b, nullptr, out32, bar1, n, NB, gw);
            }
        }
    } else {
        // fallback: fp32 global-atomic pipeline, h in d_out, x in ws
        float* x    = (float*)d_ws;
        float* hbuf = (float*)d_out;
        const int nwork = ne * DIM;
        const int edge_blocks = (nwork + BLK - 1) / BLK;
        const int x_tot4 = (n * DIM) / 4;
        const int xz_blocks = (x_tot4 + BLK - 1) / BLK;
        const int nb2 = (n + BLK - 1) / BLK;

        init_mask32_kernel<<<nb2, BLK, 0, stream>>>(h_in, hbuf, depth, n);
        zero_buf_kernel<<<xz_blocks, BLK, 0, stream>>>((float4*)x, x_tot4);
        simple_scatter_kernel<<<edge_blocks, BLK, 0, stream>>>(recv, send, hbuf, x, ne);
        gru32_kernel<<<nb2, BLK, 0, stream>>>(x, hbuf, hbuf, depth, 0, n, gw);
        zero_buf_kernel<<<xz_blocks, BLK, 0, stream>>>((float4*)x, x_tot4);
        simple_scatter_kernel<<<edge_blocks, BLK, 0, stream>>>(recv, send, hbuf, x, ne);
        gru32_kernel<<<nb2, BLK, 0, stream>>>(x, hbuf, hbuf, depth, 1, n, gw);
    }
}

// Round 20
// 555.217 us; speedup vs baseline: 4.5254x; 4.5254x over previous
//
#include <hip/hip_runtime.h>
#include <hip/hip_fp16.h>
#include <math.h>
#include <stdint.h>

#define DIM 10
#define NTILE 256
#define BKT_LOG 8
#define BKT 256                   // nodes per bucket == threads per WG
#define NBMAX 2048
#define EPW 2048                  // edges per WG in binning
#define KPT (EPW / 256)
#define CAPB 2816                 // slots per bucket
#define CAPF 1280                 // front region (mean 1024 + ~8 sigma)
#define CAPK (CAPB - CAPF)        // back region  (mean 1280 + ~7 sigma)
#define OVFCAP 32768
#define D2WORDS 32768

// meta (u32): cntF[NBMAX] | cntB[NBMAX] | ovfc[8] | ovf[OVFCAP] | depth2[D2WORDS]
// ws: h16a[n*16 u16] | h16b[n*16 u16] | bins[NB*CAPB u32] | meta

__device__ __forceinline__ float2 cvt2(uint32_t u) {
    __half2 hh = *reinterpret_cast<__half2*>(&u);
    return __half22float2(hh);
}

__device__ __forceinline__ int d2get(const uint32_t* __restrict__ depth2, int node) {
    uint32_t w = depth2[(uint32_t)node >> 4];
    return (int)((w >> ((node & 15) * 2)) & 3u);
}

// ---------------------------------------------------------------------------
// prep: blocks [0,pack_blocks) pack depth into 2-bit table;
//       blocks [pack_blocks, ...) zero the counters.
// ---------------------------------------------------------------------------
__global__ void prep_kernel(const int* __restrict__ depth,
                            uint32_t* __restrict__ depth2,
                            uint32_t* __restrict__ cnts,
                            int n, int pack_blocks, int cnt_tot)
{
    __shared__ int sd[4096];
    const int t = threadIdx.x;
    const int bid = blockIdx.x;
    if (bid < pack_blocks) {
        const int base = bid * 4096;
        for (int i = t; i < 4096; i += 256) {
            int g = base + i;
            sd[i] = (g < n) ? depth[g] : 3;
        }
        __syncthreads();
        int wb = (base >> 4) + t;
        if (wb * 16 < n) {
            uint32_t v = 0;
            #pragma unroll
            for (int j = 0; j < 16; ++j)
                v |= ((uint32_t)(sd[t * 16 + j] & 3)) << (2 * j);
            depth2[wb] = v;
        }
    } else {
        int i = (bid - pack_blocks) * 256 + t;
        if (i < cnt_tot) cnts[i] = 0;
    }
}

// ---------------------------------------------------------------------------
// binit: blocks [0,bin_blocks) = edge binning; rest = init h16a from h_in.
// ---------------------------------------------------------------------------
__global__ __launch_bounds__(256) void binit_kernel(
                           const int* __restrict__ recv,
                           const int* __restrict__ send,
                           const uint32_t* __restrict__ depth2,
                           const int* __restrict__ depth,
                           const float* __restrict__ h_in,
                           uint16_t* __restrict__ h16a,
                           uint32_t* __restrict__ cntF,
                           uint32_t* __restrict__ cntB,
                           uint32_t* __restrict__ ovfc,
                           uint32_t* __restrict__ ovf,
                           uint32_t* __restrict__ bins,
                           int ne, int n, int bin_blocks)
{
    __shared__ uint32_t u[3 * NBMAX];    // 24 KB
    const int t = threadIdx.x;
    const int bid = blockIdx.x;

    if (bid < bin_blocks) {
        uint32_t* lh  = u;
        uint32_t* wgF = u + NBMAX;
        uint32_t* wgB = u + 2 * NBMAX;
        for (int i = t; i < NBMAX; i += 256) lh[i] = 0;
        __syncthreads();

        const int base = bid * EPW;
        int rA[KPT], sA[KPT];
        #pragma unroll
        for (int k = 0; k < KPT; ++k) {
            int e = base + k * 256 + t;
            if (e < ne) { rA[k] = recv[e]; sA[k] = send[e]; }
            else        { rA[k] = -1;      sA[k] = 0;       }
        }
        int drA[KPT], dsA[KPT];
        #pragma unroll
        for (int k = 0; k < KPT; ++k) {
            if (rA[k] >= 0) { drA[k] = d2get(depth2, rA[k]); dsA[k] = d2get(depth2, sA[k]); }
            else            { drA[k] = 3;                    dsA[k] = 3;                    }
        }
        uint32_t fl = 0;
        #pragma unroll
        for (int k = 0; k < KPT; ++k) {
            if (rA[k] >= 0 && drA[k] <= 2 && dsA[k] <= 2) {
                bool f1 = (drA[k] <= 1) && (dsA[k] <= 1);
                fl |= (f1 ? 3u : 1u) << (2 * k);
                atomicAdd(&lh[rA[k] >> BKT_LOG], f1 ? 1u : 0x10000u);
            }
        }
        __syncthreads();

        for (int i = t; i < NBMAX; i += 256) {
            uint32_t v = lh[i];
            if (v) {
                uint32_t f = v & 0xffffu, kb = v >> 16;
                if (f)  wgF[i] = atomicAdd(&cntF[i], f);
                if (kb) wgB[i] = atomicAdd(&cntB[i], kb);
            }
        }
        __syncthreads();
        for (int i = t; i < NBMAX; i += 256) lh[i] = 0;   // reuse as cursors
        __syncthreads();

        #pragma unroll
        for (int k = 0; k < KPT; ++k) {
            if ((fl >> (2 * k)) & 1u) {
                int r = rA[k], s = sA[k];
                int b = r >> BKT_LOG;
                bool f1 = (fl >> (2 * k)) & 2u;
                uint32_t w = (uint32_t)s | ((uint32_t)(r & (BKT - 1)) << 19)
                           | (f1 ? (1u << 27) : 0u);
                if (f1) {
                    uint32_t o = atomicAdd(&lh[b], 1u) & 0xffffu;
                    uint32_t pos = wgF[b] + o;
                    if (pos < CAPF) bins[(size_t)b * CAPB + pos] = w;
                    else { uint32_t oi = atomicAdd(ovfc, 1u);
                           if (oi < OVFCAP) ovf[oi] = (uint32_t)(base + k * 256 + t); }
                } else {
                    uint32_t o = atomicAdd(&lh[b], 0x10000u) >> 16;
                    uint32_t pos = wgB[b] + o;
                    if (pos < CAPK) bins[(size_t)b * CAPB + (CAPB - 1) - pos] = w;
                    else { uint32_t oi = atomicAdd(ovfc, 1u);
                           if (oi < OVFCAP) ovf[oi] = (uint32_t)(base + k * 256 + t); }
                }
            }
        }
    } else {
        // init: h16a[node] = fp16( (depth<=2) ? h_in[node] : 0 ), pads 0
        float* sh = reinterpret_cast<float*>(u);
        const int tile = bid - bin_blocks;
        const int base = tile * NTILE;

        const long gbase = (long)base * DIM;
        const long glim  = (long)n * DIM;
        for (int idx = t; idx < NTILE * DIM; idx += NTILE) {
            long g = gbase + idx;
            float v = (g < glim) ? h_in[g] : 0.0f;
            sh[(idx / DIM) * 11 + (idx % DIM)] = v;
        }
        __syncthreads();

        const int node = base + t;
        if (node < n && depth[node] > 2) {
            #pragma unroll
            for (int c = 0; c < DIM; ++c) sh[t * 11 + c] = 0.0f;
        }
        __syncthreads();

        uint32_t* o16 = reinterpret_cast<uint32_t*>(h16a);
        const long o16base = (long)base * 8;
        const long o16lim  = (long)n * 8;
        for (int idx = t; idx < NTILE * 8; idx += NTILE) {
            long g = o16base + idx;
            if (g < o16lim) {
                int nl = idx / 8, c2 = idx % 8;
                uint32_t w = 0;
                if (c2 < 5) {
                    __half2 hh = __floats2half2_rn(sh[nl * 11 + 2 * c2],
                                                   sh[nl * 11 + 2 * c2 + 1]);
                    w = *reinterpret_cast<uint32_t*>(&hh);
                }
                o16[g] = w;
            }
        }
    }
}

// ---------------------------------------------------------------------------
// fused scatter + GRU, register-dieted (measured: 40 VGPR, occ ~55%,
// 269 us/dispatch — the empirical random-gather wall).
// ---------------------------------------------------------------------------
template<int ITER>
__global__ __launch_bounds__(256, 6) void scatgru_kernel(
                            const uint32_t* __restrict__ bins,
                            const uint32_t* __restrict__ cntF,
                            const uint32_t* __restrict__ cntB,
                            const uint32_t* __restrict__ ovfc,
                            const uint32_t* __restrict__ ovf,
                            const int* __restrict__ recv,
                            const int* __restrict__ send,
                            const int* __restrict__ depth,
                            const uint16_t* __restrict__ hcur,  // stride 16 halfs
                            uint16_t* __restrict__ hnext,       // ITER==0 out
                            float* __restrict__ out32,          // ITER==1 out
                            int n,
                            const float* __restrict__ Wz, const float* __restrict__ bz,
                            const float* __restrict__ Uz, const float* __restrict__ buz,
                            const float* __restrict__ Wr, const float* __restrict__ br,
                            const float* __restrict__ Ur, const float* __restrict__ bur,
                            const float* __restrict__ Wh, const float* __restrict__ bh,
                            const float* __restrict__ Uh, const float* __restrict__ buh)
{
    __shared__ float xl[BKT * DIM];      // 10240 B
    __shared__ float sW[6][100];
    __shared__ float sb[3][10];

    const int t = threadIdx.x;
    if (t < 100) {
        sW[0][t] = Wz[t]; sW[1][t] = Uz[t];
        sW[2][t] = Wr[t]; sW[3][t] = Ur[t];
        sW[4][t] = Wh[t]; sW[5][t] = Uh[t];
    }
    if (t < 10) {
        sb[0][t] = bz[t] + buz[t];
        sb[1][t] = br[t] + bur[t];
        sb[2][t] = bh[t] + buh[t];
    }
    for (int i = t; i < BKT * DIM; i += 256) xl[i] = 0.0f;
    __syncthreads();

    const int b = blockIdx.x;
    const int n0 = b << BKT_LOG;
    const int nb = min(BKT, n - n0);

    const size_t base = (size_t)b * CAPB;
    const int fc = (int)min(cntF[b], (uint32_t)CAPF);
    int tot = fc, boff = 0;
    if (ITER == 0) {
        int bc = (int)min(cntB[b], (uint32_t)CAPK);
        tot = fc + bc;
        boff = CAPB - bc - fc;
    }

    // phase 1: gather + LDS accumulate
    for (int i = t; i < tot; i += 256) {
        size_t idx = base + (size_t)((ITER == 0 && i >= fc) ? (i + boff) : i);
        uint32_t w = bins[idx];
        size_t s = (size_t)(w & 0x7FFFFu);
        uint4 q = *reinterpret_cast<const uint4*>(hcur + s * 16);
        uint32_t e8 = *reinterpret_cast<const uint32_t*>(hcur + s * 16 + 8);
        float2 f0 = cvt2(q.x), f1 = cvt2(q.y), f2 = cvt2(q.z), f3 = cvt2(q.w);
        float2 f4 = cvt2(e8);
        float* xr = xl + ((w >> 19) & (BKT - 1)) * DIM;
        atomicAdd(xr + 0, f0.x); atomicAdd(xr + 1, f0.y);
        atomicAdd(xr + 2, f1.x); atomicAdd(xr + 3, f1.y);
        atomicAdd(xr + 4, f2.x); atomicAdd(xr + 5, f2.y);
        atomicAdd(xr + 6, f3.x); atomicAdd(xr + 7, f3.y);
        atomicAdd(xr + 8, f4.x); atomicAdd(xr + 9, f4.y);
    }

    // phase 2: rare overflow edges for this bucket
    {
        const uint32_t cnt = min(*ovfc, (uint32_t)OVFCAP);
        for (uint32_t i = t; i < cnt; i += 256) {
            int e = (int)ovf[i];
            int r = recv[e];
            if ((r >> BKT_LOG) != b) continue;
            int s = send[e];
            if (ITER == 1 && (depth[r] > 1 || depth[s] > 1)) continue;
            uint4 q = *reinterpret_cast<const uint4*>(hcur + (size_t)s * 16);
            uint32_t e8v = *reinterpret_cast<const uint32_t*>(hcur + (size_t)s * 16 + 8);
            float2 f0 = cvt2(q.x), f1 = cvt2(q.y), f2 = cvt2(q.z), f3 = cvt2(q.w);
            float2 f4 = cvt2(e8v);
            float* xr = xl + (r & (BKT - 1)) * DIM;
            atomicAdd(xr + 0, f0.x); atomicAdd(xr + 1, f0.y);
            atomicAdd(xr + 2, f1.x); atomicAdd(xr + 3, f1.y);
            atomicAdd(xr + 4, f2.x); atomicAdd(xr + 5, f2.y);
            atomicAdd(xr + 6, f3.x); atomicAdd(xr + 7, f3.y);
            atomicAdd(xr + 8, f4.x); atomicAdd(xr + 9, f4.y);
        }
    }
    __syncthreads();

    // phase 3: GRU for node n0+t (register-dieted)
    if (t < nb) {
        const int node = n0 + t;
        const int dep = depth[node];
        const bool active = (dep + ITER) <= 2;

        float hv[DIM];
        {
            const uint16_t* hp = hcur + (size_t)node * 16;
            uint4 q = *reinterpret_cast<const uint4*>(hp);
            uint32_t e8v = *reinterpret_cast<const uint32_t*>(hp + 8);
            float2 f0 = cvt2(q.x), f1 = cvt2(q.y), f2 = cvt2(q.z), f3 = cvt2(q.w);
            float2 f4 = cvt2(e8v);
            hv[0] = f0.x; hv[1] = f0.y; hv[2] = f1.x; hv[3] = f1.y;
            hv[4] = f2.x; hv[5] = f2.y; hv[6] = f3.x; hv[7] = f3.y;
            hv[8] = f4.x; hv[9] = f4.y;
        }
        float xv[DIM];
        #pragma unroll
        for (int j = 0; j < DIM; ++j) xv[j] = xl[t * DIM + j];

        float zz[DIM];
        if (active) {
            // pass A: z and r; store r*h into our own xl slots (x consumed)
            #pragma unroll
            for (int i = 0; i < DIM; ++i) {
                float az = sb[0][i];
                float ar = sb[1][i];
                #pragma unroll
                for (int j = 0; j < DIM; ++j) {
                    az = fmaf(xv[j], sW[0][i * DIM + j], az);
                    az = fmaf(hv[j], sW[1][i * DIM + j], az);
                    ar = fmaf(xv[j], sW[2][i * DIM + j], ar);
                    ar = fmaf(hv[j], sW[3][i * DIM + j], ar);
                }
                zz[i] = 1.0f / (1.0f + __expf(-az));
                xl[t * DIM + i] = (1.0f / (1.0f + __expf(-ar))) * hv[i];  // rh
            }
        }

        // pass B: candidate + output, incrementally packed
        if (ITER == 0) {
            uint32_t packed[5];
            float prev = 0.0f;
            #pragma unroll
            for (int i = 0; i < DIM; ++i) {
                float o;
                if (active) {
                    float ah = sb[2][i];
                    #pragma unroll
                    for (int j = 0; j < DIM; ++j) {
                        ah = fmaf(xv[j], sW[4][i * DIM + j], ah);
                        ah = fmaf(xl[t * DIM + j], sW[5][i * DIM + j], ah);
                    }
                    o = zz[i] * hv[i] + (1.0f - zz[i]) * tanhf(ah);
                } else {
                    o = hv[i];
                }
                if (dep > 1) o = 0.0f;     // fold iter-1 mask
                if (i & 1) {
                    __half2 hh = __floats2half2_rn(prev, o);
                    packed[i >> 1] = *reinterpret_cast<uint32_t*>(&hh);
                } else prev = o;
            }
            uint4 o0 = make_uint4(packed[0], packed[1], packed[2], packed[3]);
            uint4 o1 = make_uint4(packed[4], 0u, 0u, 0u);
            *reinterpret_cast<uint4*>(hnext + (size_t)node * 16)     = o0;
            *reinterpret_cast<uint4*>(hnext + (size_t)node * 16 + 8) = o1;
        } else {
            float2* op = reinterpret_cast<float2*>(out32 + (size_t)node * DIM);
            float prev = 0.0f;
            #pragma unroll
            for (int i = 0; i < DIM; ++i) {
                float o;
                if (active) {
                    float ah = sb[2][i];
                    #pragma unroll
                    for (int j = 0; j < DIM; ++j) {
                        ah = fmaf(xv[j], sW[4][i * DIM + j], ah);
                        ah = fmaf(xl[t * DIM + j], sW[5][i * DIM + j], ah);
                    }
                    o = zz[i] * hv[i] + (1.0f - zz[i]) * tanhf(ah);
                } else {
                    o = hv[i];
                }
                if (i & 1) op[i >> 1] = make_float2(prev, o);
                else prev = o;
            }
        }
    }
}

// ---------------------------------------------------------------------------
// fallback path (ws too small / n too large): fp32 global-atomic pipeline
// ---------------------------------------------------------------------------
__global__ void init_mask32_kernel(const float* __restrict__ hsrc,
                                   float* __restrict__ hdst,
                                   const int* __restrict__ depth,
                                   int n)
{
    int node = blockIdx.x * blockDim.x + threadIdx.x;
    if (node >= n) return;
    bool act = depth[node] <= 2;
    const float* s = hsrc + (size_t)node * DIM;
    float* d = hdst + (size_t)node * DIM;
    #pragma unroll
    for (int c = 0; c < DIM; ++c) d[c] = act ? s[c] : 0.0f;
}

__global__ void simple_scatter_kernel(const int* __restrict__ recv,
                                      const int* __restrict__ send,
                                      const float* __restrict__ hm,
                                      float* __restrict__ x,
                                      int ne)
{
    const int tid = blockIdx.x * blockDim.x + threadIdx.x;
    const int e = tid / DIM;
    if (e >= ne) return;
    const int c = tid - e * DIM;
    const int s = send[e];
    const float v = hm[(size_t)s * DIM + c];
    if (v != 0.0f) {
        const int r = recv[e];
        unsafeAtomicAdd(x + (size_t)r * DIM + c, v);
    }
}

__global__ void zero_buf_kernel(float4* __restrict__ p, int tot4) {
    int i = blockIdx.x * blockDim.x + threadIdx.x;
    if (i < tot4) p[i] = make_float4(0.0f, 0.0f, 0.0f, 0.0f);
}

__global__ void gru32_kernel(const float* __restrict__ x,
                             const float* __restrict__ h,
                             float* __restrict__ out,
                             const int* __restrict__ depth, int iter, int n,
                             const float* __restrict__ Wz, const float* __restrict__ bz,
                             const float* __restrict__ Uz, const float* __restrict__ buz,
                             const float* __restrict__ Wr, const float* __restrict__ br,
                             const float* __restrict__ Ur, const float* __restrict__ bur,
                             const float* __restrict__ Wh, const float* __restrict__ bh,
                             const float* __restrict__ Uh, const float* __restrict__ buh)
{
    __shared__ float sW[6][100];
    __shared__ float sb[3][10];
    const int t = threadIdx.x;
    if (t < 100) {
        sW[0][t] = Wz[t]; sW[1][t] = Uz[t];
        sW[2][t] = Wr[t]; sW[3][t] = Ur[t];
        sW[4][t] = Wh[t]; sW[5][t] = Uh[t];
    }
    if (t < 10) {
        sb[0][t] = bz[t] + buz[t];
        sb[1][t] = br[t] + bur[t];
        sb[2][t] = bh[t] + buh[t];
    }
    __syncthreads();

    int node = blockIdx.x * blockDim.x + t;
    if (node >= n) return;
    const int dep = depth[node];
    const bool active = dep + iter <= 2;
    float xv[DIM], hv[DIM], outv[DIM];
    #pragma unroll
    for (int j = 0; j < DIM; ++j) {
        xv[j] = x[(size_t)node * DIM + j];
        hv[j] = h[(size_t)node * DIM + j];
    }
    if (active) {
        float zz[DIM], rh[DIM];
        #pragma unroll
        for (int i = 0; i < DIM; ++i) {
            float az = sb[0][i], ar = sb[1][i];
            #pragma unroll
            for (int j = 0; j < DIM; ++j) {
                az = fmaf(xv[j], sW[0][i * DIM + j], az);
                az = fmaf(hv[j], sW[1][i * DIM + j], az);
                ar = fmaf(xv[j], sW[2][i * DIM + j], ar);
                ar = fmaf(hv[j], sW[3][i * DIM + j], ar);
            }
            zz[i] = 1.0f / (1.0f + __expf(-az));
            rh[i] = (1.0f / (1.0f + __expf(-ar))) * hv[i];
        }
        #pragma unroll
        for (int i = 0; i < DIM; ++i) {
            float ah = sb[2][i];
            #pragma unroll
            for (int j = 0; j < DIM; ++j) {
                ah = fmaf(xv[j], sW[4][i * DIM + j], ah);
                ah = fmaf(rh[j], sW[5][i * DIM + j], ah);
            }
            outv[i] = zz[i] * hv[i] + (1.0f - zz[i]) * tanhf(ah);
        }
    } else {
        #pragma unroll
        for (int i = 0; i < DIM; ++i) outv[i] = hv[i];
    }
    if (iter == 0 && dep > 1) {
        #pragma unroll
        for (int i = 0; i < DIM; ++i) outv[i] = 0.0f;
    }
    #pragma unroll
    for (int i = 0; i < DIM; ++i) out[(size_t)node * DIM + i] = outv[i];
}

extern "C" void kernel_launch(void* const* d_in, const int* in_sizes, int n_in,
                              void* d_out, int out_size, void* d_ws, size_t ws_size,
                              hipStream_t stream) {
    const float* h_in  = (const float*)d_in[0];
    const int*   edges = (const int*)d_in[1];
    const int*   depth = (const int*)d_in[2];
    const float* Wz  = (const float*)d_in[3];
    const float* bz  = (const float*)d_in[4];
    const float* Uz  = (const float*)d_in[5];
    const float* buz = (const float*)d_in[6];
    const float* Wr  = (const float*)d_in[7];
    const float* br  = (const float*)d_in[8];
    const float* Ur  = (const float*)d_in[9];
    const float* bur = (const float*)d_in[10];
    const float* Wh  = (const float*)d_in[11];
    const float* bh  = (const float*)d_in[12];
    const float* Uh  = (const float*)d_in[13];
    const float* buh = (const float*)d_in[14];

    const int n  = in_sizes[0] / DIM;       // 500,000
    const int ne = in_sizes[1] / 2;         // 8,000,000
    const int* recv = edges;
    const int* send = edges + ne;

    const int NB = (n + BKT - 1) >> BKT_LOG;
    const size_t meta_words = 2 * NBMAX + 8 + OVFCAP + D2WORDS;
    const size_t need = (size_t)n * 16 * sizeof(uint16_t) * 2        // h16a + h16b
                      + (size_t)NB * CAPB * sizeof(uint32_t)         // bins
                      + meta_words * sizeof(uint32_t);

    const int BLK = 256;

    if (ws_size >= need && n <= (1 << 19) && NB <= NBMAX) {
        uint16_t* h16a = (uint16_t*)d_ws;                       // [n*16]
        uint16_t* h16b = h16a + (size_t)n * 16;                 // [n*16]
        uint32_t* bins = (uint32_t*)(h16b + (size_t)n * 16);    // [NB*CAPB]
        uint32_t* meta = bins + (size_t)NB * CAPB;
        uint32_t* cntF   = meta;
        uint32_t* cntB   = meta + NBMAX;
        uint32_t* ovfc   = meta + 2 * NBMAX;
        uint32_t* ovf    = meta + 2 * NBMAX + 8;
        uint32_t* depth2 = ovf + OVFCAP;

        const int bin_blocks  = (ne + EPW - 1) / EPW;
        const int node_blocks = (n + NTILE - 1) / NTILE;
        const int pack_blocks = (n + 4095) / 4096;
        const int cnt_tot = 2 * NBMAX + 1;
        const int cnt_blocks = (cnt_tot + 255) / 256;

        prep_kernel<<<pack_blocks + cnt_blocks, BLK, 0, stream>>>(
            depth, depth2, meta, n, pack_blocks, cnt_tot);
        binit_kernel<<<bin_blocks + node_blocks, BLK, 0, stream>>>(
            recv, send, depth2, depth, h_in, h16a,
            cntF, cntB, ovfc, ovf, bins, ne, n, bin_blocks);

        scatgru_kernel<0><<<NB, BLK, 0, stream>>>(
            bins, cntF, cntB, ovfc, ovf, recv, send, depth,
            h16a, h16b, nullptr, n,
            Wz, bz, Uz, buz, Wr, br, Ur, bur, Wh, bh, Uh, buh);

        scatgru_kernel<1><<<NB, BLK, 0, stream>>>(
            bins, cntF, cntB, ovfc, ovf, recv, send, depth,
            h16b, nullptr, (float*)d_out, n,
            Wz, bz, Uz, buz, Wr, br, Ur, bur, Wh, bh, Uh, buh);
    } else {
        // fallback: fp32 global-atomic pipeline, h in d_out, x in ws
        float* x    = (float*)d_ws;
        float* hbuf = (float*)d_out;
        const int nwork = ne * DIM;
        const int edge_blocks = (nwork + BLK - 1) / BLK;
        const int x_tot4 = (n * DIM) / 4;
        const int xz_blocks = (x_tot4 + BLK - 1) / BLK;
        const int nb2 = (n + BLK - 1) / BLK;

        init_mask32_kernel<<<nb2, BLK, 0, stream>>>(h_in, hbuf, depth, n);
        zero_buf_kernel<<<xz_blocks, BLK, 0, stream>>>((float4*)x, x_tot4);
        simple_scatter_kernel<<<edge_blocks, BLK, 0, stream>>>(recv, send, hbuf, x, ne);
        gru32_kernel<<<nb2, BLK, 0, stream>>>(x, hbuf, hbuf, depth, 0, n,
            Wz, bz, Uz, buz, Wr, br, Ur, bur, Wh, bh, Uh, buh);
        zero_buf_kernel<<<xz_blocks, BLK, 0, stream>>>((float4*)x, x_tot4);
        simple_scatter_kernel<<<edge_blocks, BLK, 0, stream>>>(recv, send, hbuf, x, ne);
        gru32_kernel<<<nb2, BLK, 0, stream>>>(x, hbuf, hbuf, depth, 1, n,
            Wz, bz, Uz, buz, Wr, br, Ur, bur, Wh, bh, Uh, buh);
    }
}